// Round 12
// baseline (208.584 us; speedup 1.0000x reference)
//
#include <hip/hip_runtime.h>
#include <cstdint>

#define BB 8192
#define TT 50
#define FF 24
#define ROWS 16
#define LOG2E 1.4426950408889634f

typedef __attribute__((ext_vector_type(8))) short short8;
typedef __attribute__((ext_vector_type(4))) float f32x4;

// sigmoid on pre-scaled input (weights carry log2e): 1/(1+2^-x).
// RAW v_exp_f32 + raw v_rcp_f32 (no OCML guards).
__device__ __forceinline__ float sig2(float xs){
  return __builtin_amdgcn_rcpf(1.0f + __builtin_amdgcn_exp2f(-xs));
}

// hardware RNE bf16 pair-convert (lo=a, hi=b); bit-identical to manual RNE
__device__ __forceinline__ unsigned cvtpk(float a, float b){
  unsigned r;
  asm("v_cvt_pk_bf16_f32 %0, %1, %2" : "=v"(r) : "v"(a), "v"(b));
  return r;
}

// single bf16 RNE -- prologue/cold paths only
__device__ __forceinline__ unsigned short rne16(float v){
  unsigned b = __float_as_uint(v);
  b += 0x7FFFu + ((b >> 16) & 1u);
  return (unsigned short)(b >> 16);
}

// counted-wait phase barrier (LDS-only drain; R15)
__device__ __forceinline__ void phase_barrier(){
  __builtin_amdgcn_sched_barrier(0);
  asm volatile("s_waitcnt lgkmcnt(0)" ::: "memory");
  __builtin_amdgcn_s_barrier();
  asm volatile("" ::: "memory");
  __builtin_amdgcn_sched_barrier(0);
}

#define MFMA(A,B,C) __builtin_amdgcn_mfma_f32_16x16x32_bf16((A),(B),(C),0,0,0)

// Round 20: the STAGGER experiment, deconfounded. R19 math (raw exp2,
// cvtpk, single-bf16 weights, K-reordered a1, shared h1 B-frags,
// 1 barrier/step) on ROWS=16 geometry: grid 512, 16 waves/block,
// HALF per-wave work (L1 1 tile/wave, L2 on waves 8-15, loop-C 1 tile).
// KEY difference vs R10 (round 10): __launch_bounds__(1024,4) -- the
// allocator keeps its natural ~50-60 VGPR (R10's (1024,8) squeezed to
// 32 + scratch spill: +31MB FETCH/+68MB WRITE, the real regression
// cause). With VGPR<=64 the HW co-schedules 2 blocks/CU at runtime ->
// two INDEPENDENT barrier groups stagger their lock-step dependency
// chains (read->MFMA->sigmoid->write->barrier) on each SIMD.
// Falsifiers: VGPR>64 (experiment void) or occupancy~80 with flat time
// (stagger refuted -> issue-mix roofline).
// a1 row layout: [0..63]=h1, [64..87]=x(t), [88..103]=pad(0).

__global__ __launch_bounds__(1024,4)
void ae_fused(
    const float* __restrict__ x,
    const float* __restrict__ W1, const float* __restrict__ U1, const float* __restrict__ b1,
    const float* __restrict__ W2, const float* __restrict__ U2, const float* __restrict__ b2,
    const float* __restrict__ W3, const float* __restrict__ U3, const float* __restrict__ b3,
    const float* __restrict__ Wd, const float* __restrict__ bd,
    float* __restrict__ out)
{
  constexpr int AS1 = 104, AS2 = 40, AS3 = 72;
  __shared__ __align__(16) unsigned short a1[2][ROWS*AS1];
  __shared__ __align__(16) unsigned short a2[2][ROWS*AS2]; // h2(32)|pad
  __shared__ __align__(16) unsigned short a3[2][ROWS*AS3]; // h3(64)|pad

  const int tid = threadIdx.x, wave = tid>>6, lane = tid&63;
  const int quad = lane>>4, li = lane&15;
  const int b0 = blockIdx.x*ROWS;

  const int gl = li & 3;                       // gate row this lane packs
  const float scl = (gl==2) ? 1.0f : LOG2E;    // g(relu) unscaled

  // ---- L1 weight A-frag (single bf16 RNE, scaled, reordered k): tile = wave ----
  short8 A1w[3];
  f32x4 bi1;
  {
    const int zc = gl*64 + 4*wave + (li>>2);
#pragma unroll
    for (int ks=0; ks<3; ++ks){
      short8 v1;
#pragma unroll
      for (int j=0; j<8; ++j){
        const int kk = quad*8 + j;
        float w;
        if (ks < 2) w = U1[(ks*32+kk)*256+zc];
        else        w = (kk<24) ? W1[kk*256+zc] : 0.f;
        v1[j] = (short)rne16(w*scl);
      }
      A1w[ks]=v1;
    }
#pragma unroll
    for (int i2=0;i2<4;++i2)
      bi1[i2] = b1[i2*64 + 4*wave + quad] * ((i2==2)?1.0f:LOG2E);
  }
  // ---- L2 weight A-frag: waves 8-15, tile w7 = wave-8 ----
  const bool hasL2 = (wave >= 8);
  const int w7 = wave & 7;
  short8 A1w2[3];
  f32x4 bi2;
  if (hasL2){
    const int zc = gl*32 + 4*w7 + (li>>2);
#pragma unroll
    for (int ks=0; ks<3; ++ks){
      short8 v1;
#pragma unroll
      for (int j=0; j<8; ++j){
        const int kk = quad*8 + j;
        float w = (ks<2) ? W2[(ks*32+kk)*128+zc] : U2[kk*128+zc];
        v1[j] = (short)rne16(w*scl);
      }
      A1w2[ks]=v1;
    }
#pragma unroll
    for (int i2=0;i2<4;++i2)
      bi2[i2] = b2[i2*32 + 4*w7 + quad] * ((i2==2)?1.0f:LOG2E);
  }

  // zero LDS (h regions read 0 at t=0; pads stay 0; a3 for loop-C)
  { unsigned* p1 = (unsigned*)a1; for (int i=tid;i<2*ROWS*AS1/2;i+=1024) p1[i]=0u;
    unsigned* p2 = (unsigned*)a2; for (int i=tid;i<2*ROWS*AS2/2;i+=1024) p2[i]=0u;
    unsigned* p3 = (unsigned*)a3; for (int i=tid;i<2*ROWS*AS3/2;i+=1024) p3[i]=0u; }
  __syncthreads();
  // stage x(0) into slot 0 (x region base = 64)
  if (tid < ROWS*FF){
    const int r = tid/FF, f = tid - r*FF;
    a1[0][r*AS1 + 64 + f] = rne16(x[((size_t)(b0+r)*TT + 0)*FF + f]);
  }
  // x prefetch (threads tid<384): va=x(t+1), vb=x(t+2)
  int pr=0, pf=0; const float* xp=nullptr;
  float va=0.f, vb=0.f;
  const bool st = (tid < ROWS*FF);
  if (st){
    pr = tid/FF; pf = tid - pr*FF;
    xp = x + (size_t)(b0+pr)*TT*FF + pf;
    va = xp[1*FF];
    vb = xp[2*FF];
  }
  float c1s = 0.f;
  float c2s = 0.f;
  const int rb1 = li*AS1;
  const int rb2 = li*AS2;
  const int hw1 = rb1 + 4*wave + quad;         // h1 write (base 0)
  const int hw2 = rb2 + 4*w7 + quad;
  __syncthreads();

  // =================== loop A: L1 + L2 ===================
#pragma unroll 1
  for (int t=0; t<=TT; ++t){
    const int s = t&1, ns = s^1;
    float vc = 0.f;
    if (st && t+3 < TT) vc = xp[(t+3)*FF];
    // shared h1 B-frags (consumed by L1 ks0,1 AND L2 ks0,1)
    short8 Bh0 = *(const short8*)&a1[s][rb1 +      quad*8];
    short8 Bh1 = *(const short8*)&a1[s][rb1 + 32 + quad*8];
    // ---- L1: z1(t) + gates -> h1(t) ----
    if (t < TT){
      short8 Bx = *(const short8*)&a1[s][rb1 + 64 + quad*8];
      f32x4 C = bi1;
      C = MFMA(A1w[0], Bh0, C);
      C = MFMA(A1w[1], Bh1, C);
      C = MFMA(A1w[2], Bx,  C);
      const float ig = sig2(C[0]), fg = sig2(C[1]);
      const float gg = fmaxf(C[2],0.f), og = sig2(C[3]);
      const float cn = fg*c1s + ig*gg; c1s = cn;
      a1[ns][hw1] = (unsigned short)cvtpk(og*fmaxf(cn,0.f), 0.f);
    }
    // ---- L2: z2(t-1) + gates -> h2(t-1) (waves 8-15) ----
    if (hasL2 && t >= 1){
      f32x4 C = bi2;
      C = MFMA(A1w2[0], Bh0, C);
      C = MFMA(A1w2[1], Bh1, C);
      {
        short8 Bh2 = *(const short8*)&a2[s][rb2 + quad*8];
        C = MFMA(A1w2[2], Bh2, C);
      }
      const float ig = sig2(C[0]), fg = sig2(C[1]);
      const float gg = fmaxf(C[2],0.f), og = sig2(C[3]);
      const float cn = fg*c2s + ig*gg; c2s = cn;
      a2[ns][hw2] = (unsigned short)cvtpk(og*fmaxf(cn,0.f), 0.f); // t==TT -> a2[1]
    }
    // ---- x staging: write x(t+1) into x region ----
    if (st && t < TT-1){
      a1[ns][pr*AS1 + 64 + pf] = (unsigned short)cvtpk(va, 0.f);
      va = vb; vb = vc;
    }
    phase_barrier();
  }

  // =================== prologue C: L3 + dense weights ===================
  short8 A1u[2];
  short8 A1w3;
  f32x4 bi3;
  {
    const int zc = gl*64 + 4*wave + (li>>2);
#pragma unroll
    for (int ks=0; ks<2; ++ks){
      short8 v1;
#pragma unroll
      for (int j=0; j<8; ++j){
        const int k = ks*32 + quad*8 + j;
        v1[j] = (short)rne16(U3[k*256+zc]*scl);
      }
      A1u[ks]=v1;
    }
    {
      short8 v1;
#pragma unroll
      for (int j=0; j<8; ++j){
        const int k = quad*8 + j;
        v1[j] = (short)rne16(W3[k*256+zc]*scl);
      }
      A1w3=v1;
    }
#pragma unroll
    for (int i2=0;i2<4;++i2)
      bi3[i2] = b3[i2*64 + 4*wave + quad] * ((i2==2)?1.0f:LOG2E);
  }
  const bool dW = (wave < 2);
  const int dcol = wave*16 + li;
  const bool dOK = dW && (dcol < 24);
  const float bdv = dOK ? bd[dcol] : 0.f;
  short8 Bd1[2];
  if (dW){
#pragma unroll
    for (int ks=0; ks<2; ++ks){
      short8 v1;
#pragma unroll
      for (int j=0; j<8; ++j){
        const int k = ks*32 + quad*8 + j;
        v1[j] = (short)rne16(dOK ? Wd[k*24+dcol] : 0.f);
      }
      Bd1[ks]=v1;
    }
  }

  // ZR = b3 + h2@W3 (h2 bf16 in a2[1], written by loop-A's t=TT phase)
  f32x4 zr;
  {
    short8 Ba = *(const short8*)&a2[1][rb2 + quad*8];
    f32x4 C = bi3;
    C = MFMA(A1w3, Ba, C);
    zr = C;
  }
  float c3s = 0.f;
  const int rb3 = li*AS3;
  const int hw3 = rb3 + 4*wave + quad;

  // =================== loop C: L3 + fused dense ===================
#pragma unroll 1
  for (int t=0; t<=TT; ++t){
    const int s = t&1, ns = s^1;
    if (t < TT){
      short8 Ba0 = *(const short8*)&a3[s][rb3 +      quad*8];
      short8 Ba1 = *(const short8*)&a3[s][rb3 + 32 + quad*8];
      f32x4 C = zr;
      C = MFMA(A1u[0], Ba0, C);
      C = MFMA(A1u[1], Ba1, C);
      const float ig = sig2(C[0]), fg = sig2(C[1]);
      const float gg = fmaxf(C[2],0.f), og = sig2(C[3]);
      const float cn = fg*c3s + ig*gg; c3s = cn;
      a3[ns][hw3] = (unsigned short)cvtpk(og*fmaxf(cn,0.f), 0.f);
      // dense on h3(t-1) (same Ba frags), out column t-1
      if (dW && t > 0){
        f32x4 Cd = {bdv,bdv,bdv,bdv};
        Cd = MFMA(Ba0, Bd1[0], Cd);
        Cd = MFMA(Ba1, Bd1[1], Cd);
        if (dcol < 24){
#pragma unroll
          for (int i2=0;i2<4;++i2)
            out[((size_t)(b0+quad*4+i2)*TT + (t-1))*FF + dcol] = Cd[i2];
        }
      }
    } else {
      // t == TT: final dense on h3(TT-1)
      if (dW){
        f32x4 Cd = {bdv,bdv,bdv,bdv};
        short8 Ba0 = *(const short8*)&a3[s][rb3 +      quad*8];
        short8 Ba1 = *(const short8*)&a3[s][rb3 + 32 + quad*8];
        Cd = MFMA(Ba0, Bd1[0], Cd);
        Cd = MFMA(Ba1, Bd1[1], Cd);
        if (dcol < 24){
#pragma unroll
          for (int i2=0;i2<4;++i2)
            out[((size_t)(b0+quad*4+i2)*TT + (TT-1))*FF + dcol] = Cd[i2];
        }
      }
    }
    phase_barrier();
  }
}

extern "C" void kernel_launch(void* const* d_in, const int* in_sizes, int n_in,
                              void* d_out, int out_size, void* d_ws, size_t ws_size,
                              hipStream_t stream){
  const float* x  = (const float*)d_in[0];
  const float* W1 = (const float*)d_in[1];
  const float* U1 = (const float*)d_in[2];
  const float* b1 = (const float*)d_in[3];
  const float* W2 = (const float*)d_in[4];
  const float* U2 = (const float*)d_in[5];
  const float* b2 = (const float*)d_in[6];
  const float* W3 = (const float*)d_in[7];
  const float* U3 = (const float*)d_in[8];
  const float* b3 = (const float*)d_in[9];
  const float* Wd = (const float*)d_in[10];
  const float* bd = (const float*)d_in[11];
  float* out = (float*)d_out;

  hipLaunchKernelGGL(ae_fused, dim3(BB/ROWS), dim3(1024), 0, stream,
                     x, W1, U1, b1, W2, U2, b2, W3, U3, b3, Wd, bd, out);
}

// Round 13
// 190.979 us; speedup vs baseline: 1.0922x; 1.0922x over previous
//
#include <hip/hip_runtime.h>
#include <cstdint>

#define BB 8192
#define TT 50
#define FF 24
#define ROWS 32
#define LOG2E 1.4426950408889634f

typedef __attribute__((ext_vector_type(8))) short short8;
typedef __attribute__((ext_vector_type(4))) float f32x4;

// sigmoid on pre-scaled input (weights carry log2e): 1/(1+2^-x).
// RAW v_exp_f32 + raw v_rcp_f32 (no OCML guards).
__device__ __forceinline__ float sig2(float xs){
  return __builtin_amdgcn_rcpf(1.0f + __builtin_amdgcn_exp2f(-xs));
}

// hardware RNE bf16 pair-convert (lo=a, hi=b); bit-identical to manual RNE
__device__ __forceinline__ unsigned cvtpk(float a, float b){
  unsigned r;
  asm("v_cvt_pk_bf16_f32 %0, %1, %2" : "=v"(r) : "v"(a), "v"(b));
  return r;
}

// single bf16 RNE -- prologue/cold paths only
__device__ __forceinline__ unsigned short rne16(float v){
  unsigned b = __float_as_uint(v);
  b += 0x7FFFu + ((b >> 16) & 1u);
  return (unsigned short)(b >> 16);
}

// phase barrier: LDS-only producer drain + block barrier. vs R19: the
// sched_barrier(0) pins are REMOVED -- all ds_read/MFMA deps here are
// compiler-emitted (tracked), so the scheduler may legally hoist
// register-only next-phase setup across the barrier (rule #18 applies
// to inline-asm ds_read, not used here).
__device__ __forceinline__ void phase_barrier(){
  asm volatile("s_waitcnt lgkmcnt(0)" ::: "memory");
  __builtin_amdgcn_s_barrier();
  asm volatile("" ::: "memory");
}

#define MFMA(A,B,C) __builtin_amdgcn_mfma_f32_16x16x32_bf16((A),(B),(C),0,0,0)

// Round 21: REVERT to R19 (best: 111.5us kernel, 193.7us harness) with
// relaxed barrier scheduling. Why revert: R20/R12 (ROWS=16, grid 512)
// regressed to 128us -- unified VGPR+AGPR footprint (~112/wave) caps the
// CU at 4 waves/SIMD, so the second block never co-resides and the
// per-phase latency floor is paid twice. Occupancy wall verified closed:
// 8 waves needs <=64 total regs (spills, R10); weights-in-LDS needs
// 164KB/CU > 160KB; weights-from-L2 needs ~107TB/s > 34.5TB/s.
// Structure: fused A+C, transposed MFMA (weights=A, acts=B), 1 barrier
// per recurrence step (102 total = minimal for the 101-step dependency
// depth), single-bf16 RNE weights+activations, raw exp2/rcp sigmoid with
// log2e folded into weights, K-reordered a1 (h1@0..63, x@64..87) so L1
// and L2 share h1 B-frags, packed cvt_pk h-writes, x register-prefetch.

__global__ __launch_bounds__(1024,4)
void ae_fused(
    const float* __restrict__ x,
    const float* __restrict__ W1, const float* __restrict__ U1, const float* __restrict__ b1,
    const float* __restrict__ W2, const float* __restrict__ U2, const float* __restrict__ b2,
    const float* __restrict__ W3, const float* __restrict__ U3, const float* __restrict__ b3,
    const float* __restrict__ Wd, const float* __restrict__ bd,
    float* __restrict__ out)
{
  constexpr int AS1 = 104, AS2 = 40, AS3 = 72;
  // a1 layout per row: [0..63]=h1, [64..87]=x(t), [88..103]=pad(0)
  __shared__ __align__(16) unsigned short a1[2][ROWS*AS1];
  __shared__ __align__(16) unsigned short a2[2][ROWS*AS2]; // h2(32)|pad
  __shared__ __align__(16) unsigned short a3[2][ROWS*AS3]; // h3(64)|pad

  const int tid = threadIdx.x, wave = tid>>6, lane = tid&63;
  const int quad = lane>>4, li = lane&15;
  const int w7 = wave&7, rg = wave>>3;
  const int b0 = blockIdx.x*ROWS;
  const int arow = rg*16 + li;

  const int gl = li & 3;                       // gate row this lane packs
  const float scl = (gl==2) ? 1.0f : LOG2E;    // g(relu) unscaled

  // ---- L1 weight A-frags (single bf16 RNE, scaled, reordered k) ----
  // u = 8*w7 + 2*(m>>2) + tp ; k: ks0,1 = U1 rows (h1), ks2 = W1 rows (x)
  short8 A1w[2][3];
  f32x4 bi1[2];
#pragma unroll
  for (int tp=0; tp<2; ++tp){
    const int zc = gl*64 + 8*w7 + 2*(li>>2) + tp;
#pragma unroll
    for (int ks=0; ks<3; ++ks){
      short8 v1;
#pragma unroll
      for (int j=0; j<8; ++j){
        const int kk = quad*8 + j;
        float w;
        if (ks < 2) w = U1[(ks*32+kk)*256+zc];
        else        w = (kk<24) ? W1[kk*256+zc] : 0.f;
        v1[j] = (short)rne16(w*scl);
      }
      A1w[tp][ks]=v1;
    }
#pragma unroll
    for (int i2=0;i2<4;++i2)
      bi1[tp][i2] = b1[i2*64 + 8*w7 + 2*quad + tp] * ((i2==2)?1.0f:LOG2E);
  }
  // ---- L2 weight A-frags: u2 = 4*w7 + (m>>2); ks0,1 = W2 rows (h1), ks2 = U2 (h2) ----
  short8 A1w2[3];
  f32x4 bi2;
  {
    const int zc = gl*32 + 4*w7 + (li>>2);
#pragma unroll
    for (int ks=0; ks<3; ++ks){
      short8 v1;
#pragma unroll
      for (int j=0; j<8; ++j){
        const int kk = quad*8 + j;
        float w = (ks<2) ? W2[(ks*32+kk)*128+zc] : U2[kk*128+zc];
        v1[j] = (short)rne16(w*scl);
      }
      A1w2[ks]=v1;
    }
#pragma unroll
    for (int i2=0;i2<4;++i2)
      bi2[i2] = b2[i2*32 + 4*w7 + quad] * ((i2==2)?1.0f:LOG2E);
  }

  // zero LDS (h regions read 0 at t=0; pads stay 0; a3 for loop-C)
  { unsigned* p1 = (unsigned*)a1; for (int i=tid;i<2*ROWS*AS1/2;i+=1024) p1[i]=0u;
    unsigned* p2 = (unsigned*)a2; for (int i=tid;i<2*ROWS*AS2/2;i+=1024) p2[i]=0u;
    unsigned* p3 = (unsigned*)a3; for (int i=tid;i<2*ROWS*AS3/2;i+=1024) p3[i]=0u; }
  __syncthreads();
  // stage x(0) into slot 0 (x region base = 64)
  if (tid < ROWS*FF){
    const int r = tid/FF, f = tid - r*FF;
    a1[0][r*AS1 + 64 + f] = rne16(x[((size_t)(b0+r)*TT + 0)*FF + f]);
  }
  // x prefetch (threads tid<768): va=x(t+1), vb=x(t+2)
  int pr=0, pf=0; const float* xp=nullptr;
  float va=0.f, vb=0.f;
  const bool st = (tid < ROWS*FF);
  if (st){
    pr = tid/FF; pf = tid - pr*FF;
    xp = x + (size_t)(b0+pr)*TT*FF + pf;
    va = xp[1*FF];
    vb = xp[2*FF];
  }
  float c1s[2] = {0.f,0.f};
  float c2s = 0.f;
  const int rb1 = arow*AS1;
  const int rb2 = arow*AS2;
  const int hw1p = rb1 + 8*w7 + 2*quad;        // h1 pair write (base 0)
  const int hw2 = rb2 + 4*w7 + quad;
  __syncthreads();

  // =================== loop A: L1 + L2 ===================
#pragma unroll 1
  for (int t=0; t<=TT; ++t){
    const int s = t&1, ns = s^1;
    float vc = 0.f;
    if (st && t+3 < TT) vc = xp[(t+3)*FF];
    // shared h1 B-frags (consumed by L1 ks0,1 AND L2 ks0,1)
    short8 Bh0 = *(const short8*)&a1[s][rb1 +      quad*8];
    short8 Bh1 = *(const short8*)&a1[s][rb1 + 32 + quad*8];
    // ---- L1: z1(t) + gates -> h1(t) ----
    if (t < TT){
      short8 Bx = *(const short8*)&a1[s][rb1 + 64 + quad*8];
      float hp[2];
#pragma unroll
      for (int tp=0; tp<2; ++tp){
        f32x4 C = bi1[tp];
        C = MFMA(A1w[tp][0], Bh0, C);
        C = MFMA(A1w[tp][1], Bh1, C);
        C = MFMA(A1w[tp][2], Bx,  C);
        const float ig = sig2(C[0]), fg = sig2(C[1]);
        const float gg = fmaxf(C[2],0.f), og = sig2(C[3]);
        const float cn = fg*c1s[tp] + ig*gg; c1s[tp] = cn;
        hp[tp] = og*fmaxf(cn,0.f);
      }
      *(unsigned*)&a1[ns][hw1p] = cvtpk(hp[0], hp[1]);
    }
    // ---- L2: z2(t-1) + gates -> h2(t-1) ----
    if (t >= 1){
      f32x4 C = bi2;
      C = MFMA(A1w2[0], Bh0, C);
      C = MFMA(A1w2[1], Bh1, C);
      {
        short8 Bh2 = *(const short8*)&a2[s][rb2 + quad*8];
        C = MFMA(A1w2[2], Bh2, C);
      }
      const float ig = sig2(C[0]), fg = sig2(C[1]);
      const float gg = fmaxf(C[2],0.f), og = sig2(C[3]);
      const float cn = fg*c2s + ig*gg; c2s = cn;
      const float h = og*fmaxf(cn,0.f);
      a2[ns][hw2] = (unsigned short)cvtpk(h, h);  // at t==TT lands in a2[1]
    }
    // ---- x staging: write x(t+1) into x region ----
    if (st && t < TT-1){
      a1[ns][pr*AS1 + 64 + pf] = (unsigned short)cvtpk(va, va);
      va = vb; vb = vc;
    }
    phase_barrier();
  }

  // =================== prologue C: L3 + dense weights ===================
  short8 A1u[2][2];
  short8 A1w3[2];
  f32x4 bi3[2];
#pragma unroll
  for (int tp=0; tp<2; ++tp){
    const int zc = gl*64 + 8*w7 + 2*(li>>2) + tp;
#pragma unroll
    for (int ks=0; ks<2; ++ks){
      short8 v1;
#pragma unroll
      for (int j=0; j<8; ++j){
        const int k = ks*32 + quad*8 + j;
        v1[j] = (short)rne16(U3[k*256+zc]*scl);
      }
      A1u[tp][ks]=v1;
    }
    {
      short8 v1;
#pragma unroll
      for (int j=0; j<8; ++j){
        const int k = quad*8 + j;
        v1[j] = (short)rne16(W3[k*256+zc]*scl);
      }
      A1w3[tp]=v1;
    }
#pragma unroll
    for (int i2=0;i2<4;++i2)
      bi3[tp][i2] = b3[i2*64 + 8*w7 + 2*quad + tp] * ((i2==2)?1.0f:LOG2E);
  }
  const bool dW = (w7 < 2);
  const int dcol = w7*16 + li;
  const bool dOK = dW && (dcol < 24);
  const float bdv = dOK ? bd[dcol] : 0.f;
  short8 Bd1[2];
  if (dW){
#pragma unroll
    for (int ks=0; ks<2; ++ks){
      short8 v1;
#pragma unroll
      for (int j=0; j<8; ++j){
        const int k = ks*32 + quad*8 + j;
        v1[j] = (short)rne16(dOK ? Wd[k*24+dcol] : 0.f);
      }
      Bd1[ks]=v1;
    }
  }

  // ZR = b3 + h2@W3 (h2 bf16 in a2[1], written by loop-A's t=TT phase)
  f32x4 zr[2];
  {
    short8 Ba = *(const short8*)&a2[1][rb2 + quad*8];
#pragma unroll
    for (int tp=0; tp<2; ++tp){
      f32x4 C = bi3[tp];
      C = MFMA(A1w3[tp], Ba, C);
      zr[tp] = C;
    }
  }
  float c3s[2] = {0.f,0.f};
  const int rb3 = arow*AS3;
  const int hw3p = rb3 + 8*w7 + 2*quad;       // pair write

  // =================== loop C: L3 + fused dense ===================
#pragma unroll 1
  for (int t=0; t<=TT; ++t){
    const int s = t&1, ns = s^1;
    if (t < TT){
      short8 Ba[2];
#pragma unroll
      for (int ks=0; ks<2; ++ks)
        Ba[ks] = *(const short8*)&a3[s][rb3 + ks*32 + quad*8];
      float hp[2];
#pragma unroll
      for (int tp=0; tp<2; ++tp){
        f32x4 C = zr[tp];
        C = MFMA(A1u[tp][0], Ba[0], C);
        C = MFMA(A1u[tp][1], Ba[1], C);
        const float ig = sig2(C[0]), fg = sig2(C[1]);
        const float gg = fmaxf(C[2],0.f), og = sig2(C[3]);
        const float cn = fg*c3s[tp] + ig*gg; c3s[tp] = cn;
        hp[tp] = og*fmaxf(cn,0.f);
      }
      *(unsigned*)&a3[ns][hw3p] = cvtpk(hp[0], hp[1]);
      // dense on h3(t-1) (same Ba frags), out column t-1
      if (dW && t > 0){
        f32x4 Cd = {bdv,bdv,bdv,bdv};
        Cd = MFMA(Ba[0], Bd1[0], Cd);
        Cd = MFMA(Ba[1], Bd1[1], Cd);
        if (dcol < 24){
#pragma unroll
          for (int i2=0;i2<4;++i2)
            out[((size_t)(b0+rg*16+quad*4+i2)*TT + (t-1))*FF + dcol] = Cd[i2];
        }
      }
    } else {
      // t == TT: final dense on h3(TT-1)
      if (dW){
        f32x4 Cd = {bdv,bdv,bdv,bdv};
#pragma unroll
        for (int ks=0; ks<2; ++ks){
          short8 Ba = *(const short8*)&a3[s][rb3 + ks*32 + quad*8];
          Cd = MFMA(Ba, Bd1[ks], Cd);
        }
        if (dcol < 24){
#pragma unroll
          for (int i2=0;i2<4;++i2)
            out[((size_t)(b0+rg*16+quad*4+i2)*TT + (TT-1))*FF + dcol] = Cd[i2];
        }
      }
    }
    phase_barrier();
  }
}

extern "C" void kernel_launch(void* const* d_in, const int* in_sizes, int n_in,
                              void* d_out, int out_size, void* d_ws, size_t ws_size,
                              hipStream_t stream){
  const float* x  = (const float*)d_in[0];
  const float* W1 = (const float*)d_in[1];
  const float* U1 = (const float*)d_in[2];
  const float* b1 = (const float*)d_in[3];
  const float* W2 = (const float*)d_in[4];
  const float* U2 = (const float*)d_in[5];
  const float* b2 = (const float*)d_in[6];
  const float* W3 = (const float*)d_in[7];
  const float* U3 = (const float*)d_in[8];
  const float* b3 = (const float*)d_in[9];
  const float* Wd = (const float*)d_in[10];
  const float* bd = (const float*)d_in[11];
  float* out = (float*)d_out;

  hipLaunchKernelGGL(ae_fused, dim3(BB/ROWS), dim3(1024), 0, stream,
                     x, W1, U1, b1, W2, U2, b2, W3, U3, b3, Wd, bd, out);
}